// Round 1
// 3726.848 us; speedup vs baseline: 1.5890x; 1.5890x over previous
//
#include <hip/hip_runtime.h>
#include <hip/hip_bf16.h>
#include <math.h>

// Problem constants
#define B_  2
#define T_  512
#define C_  768
#define H_  12
#define V_  50304
#define L_  12
#define HD_ 64
#define M_  (B_*T_)          // 1024 rows of activations

#define EPI_QKV  0   // out f32 = v + bias[n]
#define EPI_GELU 1   // out bf16 = gelu(v + bias[n])
#define EPI_RES  2   // out f32 = res[m,n] + v + bias[n]
#define EPI_DIST 3   // out f32 = (bias[n] + res[m] - 2v)/C

typedef __attribute__((ext_vector_type(8))) short short8;
typedef __attribute__((ext_vector_type(4))) float f32x4;

// ---------- helpers ----------
__device__ __forceinline__ unsigned short f2bf(float f) {
    unsigned int u = __float_as_uint(f);
    unsigned int r = (u + 0x7fffu + ((u >> 16) & 1u)) >> 16;
    return (unsigned short)r;
}

__device__ __forceinline__ float gelu_f(float t) {
    return 0.5f * t * (1.0f + tanhf(0.7978845608028654f * (t + 0.044715f * t * t * t)));
}

__device__ __forceinline__ void gld_lds16(const void* g, void* l) {
    __builtin_amdgcn_global_load_lds(
        (const __attribute__((address_space(1))) unsigned int*)g,
        (__attribute__((address_space(3))) unsigned int*)l,
        16, 0, 0);
}

__device__ __forceinline__ short8 pack8(float4 a, float4 b) {
    short8 t;
    t[0] = (short)f2bf(a.x); t[1] = (short)f2bf(a.y);
    t[2] = (short)f2bf(a.z); t[3] = (short)f2bf(a.w);
    t[4] = (short)f2bf(b.x); t[5] = (short)f2bf(b.y);
    t[6] = (short)f2bf(b.z); t[7] = (short)f2bf(b.w);
    return t;
}

// ---------- f32 -> bf16 conversion (vector x4), n % 4 == 0 ----------
__global__ __launch_bounds__(256) void cvt_k(const float* __restrict__ src,
                                             unsigned short* __restrict__ dst,
                                             int n4)
{
    for (int i = blockIdx.x * 256 + threadIdx.x; i < n4; i += gridDim.x * 256) {
        float4 v = *(const float4*)(src + (size_t)i * 4);
        ushort4 o;
        o.x = f2bf(v.x); o.y = f2bf(v.y); o.z = f2bf(v.z); o.w = f2bf(v.w);
        *(ushort4*)(dst + (size_t)i * 4) = o;
    }
}

// ---------------- embedding ----------------
__global__ __launch_bounds__(256) void embed_k(const int* __restrict__ idx,
                                               const float* __restrict__ wte,
                                               const float* __restrict__ wpe,
                                               float* __restrict__ x)
{
    int row = blockIdx.x;
    int t   = row & (T_-1);
    int tok = idx[row];
    const float* wt = wte + (size_t)tok * C_;
    const float* wp = wpe + (size_t)t   * C_;
    float* xr = x + (size_t)row * C_;
    for (int i = threadIdx.x; i < C_; i += 256)
        xr[i] = wt[i] + wp[i];
}

// ---------------- layernorm: f32 in -> bf16 out (+optional sumsq) ----------
__global__ __launch_bounds__(256) void ln_k(const float* __restrict__ x,
                                            const float* __restrict__ w,
                                            const float* __restrict__ bb,
                                            unsigned short* __restrict__ out,
                                            float* __restrict__ xx_out)
{
    int row = blockIdx.x, tid = threadIdx.x;
    __shared__ float buf[C_];
    __shared__ float red[256];
    const float* xr = x + (size_t)row * C_;

    float ls = 0.f;
    for (int i = tid; i < C_; i += 256) { float v = xr[i]; buf[i] = v; ls += v; }
    red[tid] = ls; __syncthreads();
    for (int s = 128; s > 0; s >>= 1) { if (tid < s) red[tid] += red[tid+s]; __syncthreads(); }
    float mean = red[0] * (1.f / C_);
    __syncthreads();

    float lv = 0.f;
    for (int i = tid; i < C_; i += 256) { float d = buf[i] - mean; lv += d*d; }
    red[tid] = lv; __syncthreads();
    for (int s = 128; s > 0; s >>= 1) { if (tid < s) red[tid] += red[tid+s]; __syncthreads(); }
    float rstd = 1.0f / sqrtf(red[0] * (1.f / C_) + 1e-5f);
    __syncthreads();

    float lss = 0.f;
    unsigned short* orow = out + (size_t)row * C_;
    for (int i = tid; i < C_; i += 256) {
        float o = (buf[i] - mean) * rstd * w[i] + bb[i];
        orow[i] = f2bf(o);
        lss += o * o;
    }
    if (xx_out) {
        red[tid] = lss; __syncthreads();
        for (int s = 128; s > 0; s >>= 1) { if (tid < s) red[tid] += red[tid+s]; __syncthreads(); }
        if (tid == 0) xx_out[row] = red[0];
    }
}

// ---------------- bf16 MFMA NT GEMM (m97 structure) ----------------
// C[m,n] = sum_k A[m,k]*Bw[n,k]; A [M,K] bf16, Bw [N,K] bf16.
// 128x128 tile, 4 waves, 4x4 frags of mfma_f32_16x16x32_bf16, BK=32,
// global_load_lds width-16 staging, single-buffered LDS.
__global__ __launch_bounds__(256) void gemm_bf16(
    const unsigned short* __restrict__ A,
    const unsigned short* __restrict__ Bw,
    const float* __restrict__ bias,
    const float* __restrict__ res,
    float* __restrict__ outF,
    unsigned short* __restrict__ outB,
    int M, int N, int K, int epi)
{
    __shared__ unsigned short As[128 * 32];
    __shared__ unsigned short Bs[128 * 32];
    const int tid = threadIdx.x;
    const int wv = tid >> 6, ln = tid & 63;
    const int lr = ln >> 2, lk = ln & 3;   // 16 rows x 4 k-chunks per wave pass
    const int row0 = blockIdx.y * 128, col0 = blockIdx.x * 128;

    const unsigned short* gA0 = A  + (size_t)(row0 + wv*16 + lr) * K + lk*8;
    const unsigned short* gA1 = gA0 + (size_t)64 * K;
    const unsigned short* gB0 = Bw + (size_t)(col0 + wv*16 + lr) * K + lk*8;
    const unsigned short* gB1 = gB0 + (size_t)64 * K;
    unsigned short* lA0 = As + (wv*16 + lr)*32 + lk*8;
    unsigned short* lA1 = lA0 + 64*32;
    unsigned short* lB0 = Bs + (wv*16 + lr)*32 + lk*8;
    unsigned short* lB1 = lB0 + 64*32;

    const int wr = (wv >> 1) * 64, wc = (wv & 1) * 64;
    const int fr = ln & 15, qd = ln >> 4;

    f32x4 acc[4][4] = {};

    for (int k0 = 0; k0 < K; k0 += 32) {
        gld_lds16(gA0 + k0, lA0);
        gld_lds16(gA1 + k0, lA1);
        gld_lds16(gB0 + k0, lB0);
        gld_lds16(gB1 + k0, lB1);
        __syncthreads();

        short8 af[4], bfm[4];
        #pragma unroll
        for (int i = 0; i < 4; i++)
            af[i] = *(const short8*)(As + (wr + i*16 + fr)*32 + qd*8);
        #pragma unroll
        for (int j = 0; j < 4; j++)
            bfm[j] = *(const short8*)(Bs + (wc + j*16 + fr)*32 + qd*8);
        #pragma unroll
        for (int i = 0; i < 4; i++)
            #pragma unroll
            for (int j = 0; j < 4; j++)
                acc[i][j] = __builtin_amdgcn_mfma_f32_16x16x32_bf16(af[i], bfm[j], acc[i][j], 0, 0, 0);
        __syncthreads();
    }

    // epilogue: D[row = qd*4+reg (+i*16)][col = fr (+j*16)]
    #pragma unroll
    for (int i = 0; i < 4; i++) {
        #pragma unroll
        for (int j = 0; j < 4; j++) {
            int n = col0 + wc + j*16 + fr;
            float bn = bias[n];
            f32x4 v = acc[i][j];
            #pragma unroll
            for (int r = 0; r < 4; r++) {
                int m = row0 + wr + i*16 + qd*4 + r;
                float val = v[r];
                if (epi == EPI_QKV)
                    outF[(size_t)m * N + n] = val + bn;
                else if (epi == EPI_GELU)
                    outB[(size_t)m * N + n] = f2bf(gelu_f(val + bn));
                else if (epi == EPI_RES)
                    outF[(size_t)m * N + n] = res[(size_t)m * N + n] + val + bn;
                else // EPI_DIST
                    outF[(size_t)m * N + n] = (bn + res[m] - 2.f * val) * (1.f / C_);
            }
        }
    }
}

// ---------------- fused causal flash-attention, MFMA bf16 ----------------
// qkv f32 [B*T][3C] in, y bf16 [B*T][C] out.
// Grid (T/64, H, B); 256 threads = 4 waves; wave w owns q-rows qt*64+w*16..+15.
// K-tile = 64 keys staged in LDS (bf16, stride 72 to kill bank conflicts),
// V staged transposed [d][key]. S = QK^T and PV via mfma_f32_16x16x32_bf16
// (same NT fragment layout as gemm_bf16). Online softmax in f32 registers;
// P re-laid-out via a per-wave LDS tile to feed the PV A-operand.
#define KSTR 72

__global__ __launch_bounds__(256) void attn_k(const float* __restrict__ qkv,
                                              unsigned short* __restrict__ y)
{
    const int qt = blockIdx.x, h = blockIdx.y, b = blockIdx.z;
    const int tid = threadIdx.x;
    const int wv = tid >> 6, ln = tid & 63;
    const int fr = ln & 15, qd = ln >> 4;

    __shared__ unsigned short Ks[64 * KSTR];   // [key][d]
    __shared__ unsigned short Vt[64 * KSTR];   // [d][key]
    __shared__ unsigned short Ps[64 * KSTR];   // [q_local][key]  (per-wave rows)

    const size_t rs = 3 * C_;
    const int q0 = qt * 64;

    // ---- Q fragments: held in registers for the whole kernel ----
    // A-frag layout: row = lane&15, k-chunk = (lane>>4)*8 (+32 for second mfma)
    const float* qrow = qkv + (size_t)(b * T_ + q0 + wv*16 + fr) * rs + h * HD_;
    short8 aq[2];
    #pragma unroll
    for (int c = 0; c < 2; c++) {
        float4 v0 = *(const float4*)(qrow + c*32 + qd*8);
        float4 v1 = *(const float4*)(qrow + c*32 + qd*8 + 4);
        aq[c] = pack8(v0, v1);
    }

    f32x4 yacc[4] = {};                       // [d-subtile]; rows qd*4+r, cols jd*16+fr
    float mrun[4] = {-1e30f, -1e30f, -1e30f, -1e30f};
    float lsum[4] = {0.f, 0.f, 0.f, 0.f};

    for (int kt = 0; kt <= qt; kt++) {
        __syncthreads();   // previous iteration's reads of Ks/Vt done
        // ---- stage K tile [key][d] and V^T tile [d][key] ----
        {
            int key = tid >> 2, g = tid & 3, d0 = g * 16;
            const float* kr = qkv + (size_t)(b * T_ + kt*64 + key) * rs + C_ + h * HD_ + d0;
            float4 a0 = ((const float4*)kr)[0];
            float4 a1 = ((const float4*)kr)[1];
            float4 a2 = ((const float4*)kr)[2];
            float4 a3 = ((const float4*)kr)[3];
            *(short8*)(Ks + key*KSTR + d0)     = pack8(a0, a1);
            *(short8*)(Ks + key*KSTR + d0 + 8) = pack8(a2, a3);
            const float* vr = kr + C_;
            float4 b0 = ((const float4*)vr)[0];
            float4 b1 = ((const float4*)vr)[1];
            float4 b2 = ((const float4*)vr)[2];
            float4 b3 = ((const float4*)vr)[3];
            float vv[16] = {b0.x,b0.y,b0.z,b0.w, b1.x,b1.y,b1.z,b1.w,
                            b2.x,b2.y,b2.z,b2.w, b3.x,b3.y,b3.z,b3.w};
            #pragma unroll
            for (int jj = 0; jj < 16; jj++)
                Vt[(d0 + jj)*KSTR + key] = f2bf(vv[jj]);
        }
        __syncthreads();

        // ---- S = Q K^T * scale (4 key-subtiles of 16) ----
        f32x4 sacc[4];
        #pragma unroll
        for (int j = 0; j < 4; j++) {
            short8 bk0 = *(const short8*)(Ks + (j*16 + fr)*KSTR + qd*8);
            short8 bk1 = *(const short8*)(Ks + (j*16 + fr)*KSTR + 32 + qd*8);
            f32x4 z = {};
            z = __builtin_amdgcn_mfma_f32_16x16x32_bf16(aq[0], bk0, z, 0, 0, 0);
            z = __builtin_amdgcn_mfma_f32_16x16x32_bf16(aq[1], bk1, z, 0, 0, 0);
            sacc[j] = z;
        }
        // scale + causal mask (diagonal tile only)
        #pragma unroll
        for (int j = 0; j < 4; j++) {
            #pragma unroll
            for (int r = 0; r < 4; r++) {
                float s = sacc[j][r] * 0.125f;
                if (kt == qt && (j*16 + fr) > (wv*16 + qd*4 + r)) s = -1e30f;
                sacc[j][r] = s;
            }
        }

        // ---- online softmax ----
        // row max over this tile: max over 4 subtiles, then over the 16 lanes
        // of the qd-group (cols). All 16 lanes end with the same value.
        float mt[4];
        #pragma unroll
        for (int r = 0; r < 4; r++) {
            float m0 = fmaxf(fmaxf(sacc[0][r], sacc[1][r]),
                             fmaxf(sacc[2][r], sacc[3][r]));
            #pragma unroll
            for (int off = 1; off < 16; off <<= 1)
                m0 = fmaxf(m0, __shfl_xor(m0, off));
            mt[r] = m0;
        }
        #pragma unroll
        for (int r = 0; r < 4; r++) {
            float Mn = fmaxf(mrun[r], mt[r]);
            float c = __expf(mrun[r] - Mn);
            mrun[r] = Mn;
            lsum[r] *= c;
            #pragma unroll
            for (int jd = 0; jd < 4; jd++) yacc[jd][r] *= c;
        }
        // P = exp(S - m), per-lane partial row-sum, P -> LDS (bf16) for PV A-op
        #pragma unroll
        for (int j = 0; j < 4; j++) {
            #pragma unroll
            for (int r = 0; r < 4; r++) {
                float pv = __expf(sacc[j][r] - mrun[r]);
                lsum[r] += pv;
                Ps[(wv*16 + qd*4 + r)*KSTR + j*16 + fr] = f2bf(pv);
            }
        }
        __syncthreads();   // order Ps writes before A-frag reads (cheap safety)

        // ---- PV: yacc += P * V ----
        short8 pa0 = *(const short8*)(Ps + (wv*16 + fr)*KSTR + qd*8);
        short8 pa1 = *(const short8*)(Ps + (wv*16 + fr)*KSTR + 32 + qd*8);
        #pragma unroll
        for (int jd = 0; jd < 4; jd++) {
            short8 bv0 = *(const short8*)(Vt + (jd*16 + fr)*KSTR + qd*8);
            short8 bv1 = *(const short8*)(Vt + (jd*16 + fr)*KSTR + 32 + qd*8);
            yacc[jd] = __builtin_amdgcn_mfma_f32_16x16x32_bf16(pa0, bv0, yacc[jd], 0, 0, 0);
            yacc[jd] = __builtin_amdgcn_mfma_f32_16x16x32_bf16(pa1, bv1, yacc[jd], 0, 0, 0);
        }
    }

    // ---- finalize: reduce row sums across the 16-lane group, normalize, store
    float inv[4];
    #pragma unroll
    for (int r = 0; r < 4; r++) {
        float s = lsum[r];
        #pragma unroll
        for (int off = 1; off < 16; off <<= 1)
            s += __shfl_xor(s, off);
        inv[r] = 1.f / s;
    }
    const int qa = q0 + wv*16 + qd*4;
    #pragma unroll
    for (int jd = 0; jd < 4; jd++) {
        #pragma unroll
        for (int r = 0; r < 4; r++) {
            y[(size_t)(b * T_ + qa + r) * C_ + h * HD_ + jd*16 + fr] =
                f2bf(yacc[jd][r] * inv[r]);
        }
    }
}

// ---------------- head helpers ----------------
__global__ __launch_bounds__(256) void rowsq_k(const float* __restrict__ w, float* __restrict__ out)
{
    int row = blockIdx.x, tid = threadIdx.x;
    __shared__ float red[256];
    const float* wr = w + (size_t)row * C_;
    float ls = 0.f;
    for (int i = tid; i < C_; i += 256) { float v = wr[i]; ls += v * v; }
    red[tid] = ls; __syncthreads();
    for (int s = 128; s > 0; s >>= 1) { if (tid < s) red[tid] += red[tid+s]; __syncthreads(); }
    if (tid == 0) out[row] = red[0];
}

__global__ __launch_bounds__(256) void rowmin_k(const float* __restrict__ d, float* __restrict__ dmin)
{
    int row = blockIdx.x, tid = threadIdx.x;
    __shared__ float red[256];
    const float* dr = d + (size_t)row * V_;
    float lm = 3.4e38f;
    for (int v = tid; v < V_; v += 256) lm = fminf(lm, dr[v]);
    red[tid] = lm; __syncthreads();
    for (int s = 128; s > 0; s >>= 1) { if (tid < s) red[tid] = fminf(red[tid], red[tid+s]); __syncthreads(); }
    if (tid == 0) dmin[row] = red[0];
}

__global__ __launch_bounds__(256) void rowsum_k(const float* __restrict__ d,
                                                const float* __restrict__ dmin,
                                                float* __restrict__ dsum)
{
    int row = blockIdx.x, tid = threadIdx.x;
    __shared__ float red[256];
    const float* dr = d + (size_t)row * V_;
    float mn = dmin[row];
    float ls = 0.f;
    for (int v = tid; v < V_; v += 256) {
        float r = dr[v] / mn;
        ls += exp2f(-768.f * log2f(r));
    }
    red[tid] = ls; __syncthreads();
    for (int s = 128; s > 0; s >>= 1) { if (tid < s) red[tid] += red[tid+s]; __syncthreads(); }
    if (tid == 0) dsum[row] = red[0];
}

__global__ __launch_bounds__(256) void logits_k(float* __restrict__ d,
                                                const float* __restrict__ dmin,
                                                const float* __restrict__ dsum)
{
    int m = blockIdx.y;
    int v = blockIdx.x * 256 + threadIdx.x;
    if (v >= V_) return;
    size_t i = (size_t)m * V_ + v;
    float r = d[i] / dmin[m];
    float val = exp2f(-768.f * log2f(r));
    float prob = val / dsum[m] + (0.01f / 50304.f);
    d[i] = logf(prob);
}

// ---------------- launch ----------------
static inline size_t align256(size_t x) { return (x + 255) & ~(size_t)255; }

extern "C" void kernel_launch(void* const* d_in, const int* in_sizes, int n_in,
                              void* d_out, int out_size, void* d_ws, size_t ws_size,
                              hipStream_t stream)
{
    (void)in_sizes; (void)n_in; (void)out_size; (void)ws_size;
    const int*   idx    = (const int*)  d_in[0];
    const float* wte    = (const float*)d_in[1];
    const float* wpe    = (const float*)d_in[2];
    const float* ln1_w  = (const float*)d_in[3];
    const float* ln1_b  = (const float*)d_in[4];
    const float* attn_w = (const float*)d_in[5];
    const float* attn_b = (const float*)d_in[6];
    const float* proj_w = (const float*)d_in[7];
    const float* proj_b = (const float*)d_in[8];
    const float* ln2_w  = (const float*)d_in[9];
    const float* ln2_b  = (const float*)d_in[10];
    const float* fc_w   = (const float*)d_in[11];
    const float* fc_b   = (const float*)d_in[12];
    const float* fc2_w  = (const float*)d_in[13];
    const float* fc2_b  = (const float*)d_in[14];
    const float* lnf_w  = (const float*)d_in[15];
    const float* lnf_b  = (const float*)d_in[16];

    float* dout = (float*)d_out;

    // workspace layout
    char* p = (char*)d_ws;
    size_t off = 0;
    float* x    = (float*)(p + off); off = align256(off + (size_t)M_*C_*4);
    float* qkv  = (float*)(p + off); off = align256(off + (size_t)M_*3*C_*4);
    float* xx   = (float*)(p + off); off = align256(off + (size_t)M_*4);
    float* ww   = (float*)(p + off); off = align256(off + (size_t)V_*4);
    float* dmin = (float*)(p + off); off = align256(off + (size_t)M_*4);
    float* dsum = (float*)(p + off); off = align256(off + (size_t)M_*4);
    unsigned short* h     = (unsigned short*)(p + off); off = align256(off + (size_t)M_*C_*2);
    unsigned short* y     = (unsigned short*)(p + off); off = align256(off + (size_t)M_*C_*2);
    unsigned short* hm    = (unsigned short*)(p + off); off = align256(off + (size_t)M_*4*C_*2);
    unsigned short* wte16 = (unsigned short*)(p + off); off = align256(off + (size_t)V_*C_*2);
    unsigned short* wbuf  = (unsigned short*)(p + off); off = align256(off + (size_t)9216*C_*2);

    const size_t nAttn = (size_t)3*C_*C_;    // 1769472
    const size_t nProj = (size_t)C_*C_;      //  589824
    const size_t nFc   = (size_t)4*C_*C_;    // 2359296
    const size_t nFc2  = (size_t)4*C_*C_;    // 2359296
    unsigned short* w_attn = wbuf;
    unsigned short* w_proj = w_attn + nAttn;
    unsigned short* w_fc   = w_proj + nProj;
    unsigned short* w_fc2  = w_fc   + nFc;

    // wte bf16 + ww (independent of layer loop)
    cvt_k<<<4096, 256, 0, stream>>>(wte, wte16, (int)((size_t)V_*C_/4));
    rowsq_k<<<V_, 256, 0, stream>>>(wte, ww);

    embed_k<<<M_, 256, 0, stream>>>(idx, wte, wpe, x);

    for (int l = 0; l < L_; l++) {
        // per-layer weight conversion (packed)
        cvt_k<<<1728, 256, 0, stream>>>(attn_w + (size_t)l*nAttn, w_attn, (int)(nAttn/4));
        cvt_k<<<576,  256, 0, stream>>>(proj_w + (size_t)l*nProj, w_proj, (int)(nProj/4));
        cvt_k<<<2304, 256, 0, stream>>>(fc_w   + (size_t)l*nFc,   w_fc,   (int)(nFc/4));
        cvt_k<<<2304, 256, 0, stream>>>(fc2_w  + (size_t)l*nFc2,  w_fc2,  (int)(nFc2/4));

        // attention block
        ln_k<<<M_, 256, 0, stream>>>(x, ln1_w + (size_t)l*C_, ln1_b + (size_t)l*C_, h, nullptr);
        gemm_bf16<<<dim3(3*C_/128, M_/128), 256, 0, stream>>>(
            h, w_attn, attn_b + (size_t)l*3*C_, nullptr, qkv, nullptr,
            M_, 3*C_, C_, EPI_QKV);
        attn_k<<<dim3(T_/64, H_, B_), 256, 0, stream>>>(qkv, y);
        gemm_bf16<<<dim3(C_/128, M_/128), 256, 0, stream>>>(
            y, w_proj, proj_b + (size_t)l*C_, x, x, nullptr,
            M_, C_, C_, EPI_RES);
        // MLP block
        ln_k<<<M_, 256, 0, stream>>>(x, ln2_w + (size_t)l*C_, ln2_b + (size_t)l*C_, h, nullptr);
        gemm_bf16<<<dim3(4*C_/128, M_/128), 256, 0, stream>>>(
            h, w_fc, fc_b + (size_t)l*4*C_, nullptr, nullptr, hm,
            M_, 4*C_, C_, EPI_GELU);
        gemm_bf16<<<dim3(C_/128, M_/128), 256, 0, stream>>>(
            hm, w_fc2, fc2_b + (size_t)l*C_, x, x, nullptr,
            M_, C_, 4*C_, EPI_RES);
    }

    // final LN (+ xx = row sum of squares of normalized output)
    ln_k<<<M_, 256, 0, stream>>>(x, lnf_w, lnf_b, h, xx);
    // distance head GEMM: d = (ww[n] + xx[m] - 2*<h, wte_n>)/C
    gemm_bf16<<<dim3(V_/128, M_/128), 256, 0, stream>>>(
        h, wte16, ww, xx, dout, nullptr,
        M_, V_, C_, EPI_DIST);
    // row min, row sum of d^-768, then in-place logits
    rowmin_k<<<M_, 256, 0, stream>>>(dout, dmin);
    rowsum_k<<<M_, 256, 0, stream>>>(dout, dmin, dsum);
    logits_k<<<dim3((V_ + 255)/256, M_), 256, 0, stream>>>(dout, dmin, dsum);
}